// Round 1
// baseline (338.364 us; speedup 1.0000x reference)
//
#include <hip/hip_runtime.h>

// ---------------------------------------------------------------------------
// MultiHeadSelfAttention  B=4 L=2048 D=1024 H=16 hd=64, fp32 in/out.
//   prep:      x,W -> bf16; rope tables
//   gemm<0>:   Q (rope*0.125*log2e fused), K (rope fused), Vt ([B,H,64,L])
//   attn v8:   = v7 minus the P LDS round-trip. QK^T A-operand rows are fed
//              through a bit2<->bit3 permutation (slr) so that one
//              v_permlane32_swap_b32 per u32-pair turns the packed-bf16 P
//              fragments directly into the PV B-fragment (T12 generalized to
//              16x16). Rowsum via ones-MFMA into accS (kills VALU adds + the
//              final shfl reduce). V staging XOR upgraded to
//              ((vrow>>2)^vrow)&3 -> conflict-free ds_read_b128 on PV.
//              LDS 26KB -> 16KB. setprio(1) around MFMA clusters (T5).
//   reduce:    O = (O0+O1)/(l0+l1)
//   gemm<1>:   d_out = O @ Wo^T
// R3: no forced min-waves (spills). R4: no reg prefetch (occupancy). R5: no
// per-lane scattered K/V globals. R6: LDS size was the occupancy cap.
// ---------------------------------------------------------------------------

typedef __bf16 bf16_t;
typedef __bf16 bf16x8 __attribute__((ext_vector_type(8)));
typedef __bf16 bf16x4 __attribute__((ext_vector_type(4)));
typedef float  floatx4 __attribute__((ext_vector_type(4)));
typedef unsigned int u32x2 __attribute__((ext_vector_type(2)));

#define B_  4
#define L_  2048
#define D_  1024
#define H_  16
#define HD_ 64
#define M_  (B_*L_)

__device__ __forceinline__ void async_copy16(const bf16_t* g, bf16_t* l) {
  __builtin_amdgcn_global_load_lds(
      (const __attribute__((address_space(1))) void*)g,
      (__attribute__((address_space(3))) void*)l, 16, 0, 0);
}

__device__ __forceinline__ unsigned int pack_bf16(float a, float b) {
  unsigned short ua = __builtin_bit_cast(unsigned short, (bf16_t)a);
  unsigned short ub = __builtin_bit_cast(unsigned short, (bf16_t)b);
  return (unsigned int)ua | ((unsigned int)ub << 16);
}

// ------------------------------ prep ---------------------------------------
__global__ void prep_kernel(const float* __restrict__ x,
                            const float* __restrict__ wq, const float* __restrict__ wk,
                            const float* __restrict__ wv, const float* __restrict__ wo,
                            bf16_t* __restrict__ xb,
                            bf16_t* __restrict__ wqb, bf16_t* __restrict__ wkb,
                            bf16_t* __restrict__ wvb, bf16_t* __restrict__ wob,
                            float* __restrict__ cosT, float* __restrict__ sinT)
{
  const int NX = M_*D_;
  const int NW = D_*D_;
  int i = blockIdx.x*256 + threadIdx.x;
  if (i < NX) { xb[i] = (bf16_t)x[i]; return; }
  i -= NX;
  if (i < NW) { wqb[i] = (bf16_t)wq[i]; return; }
  i -= NW;
  if (i < NW) { wkb[i] = (bf16_t)wk[i]; return; }
  i -= NW;
  if (i < NW) { wvb[i] = (bf16_t)wv[i]; return; }
  i -= NW;
  if (i < NW) { wob[i] = (bf16_t)wo[i]; return; }
  i -= NW;
  if (i < L_*32) {
    int l = i >> 5, f = i & 31;
    double inv = pow(10000.0, -(double)f / 32.0);
    double ang = (double)l * inv;
    cosT[i] = (float)cos(ang);
    sinT[i] = (float)sin(ang);
  }
}

// ------------------------------ GEMM (C = A * W^T) -------------------------
template<int MODE>
__global__ __launch_bounds__(256) void gemm_kernel(
    const bf16_t* __restrict__ A,
    const bf16_t* __restrict__ W0, const bf16_t* __restrict__ W1, const bf16_t* __restrict__ W2,
    bf16_t* __restrict__ C0, bf16_t* __restrict__ C1, bf16_t* __restrict__ C2,
    float* __restrict__ Cf,
    const float* __restrict__ cosT, const float* __restrict__ sinT)
{
  __shared__ __align__(16) bf16_t As[128*64];
  __shared__ __align__(16) bf16_t Bs[128*64];
  const int KD = 1024, ND = 1024;
  int z = (MODE==0) ? (int)blockIdx.z : 0;
  const bf16_t* W = (MODE==1) ? W0 : (z==0 ? W0 : (z==1 ? W1 : W2));
  int m0 = blockIdx.y*128, n0 = blockIdx.x*128;
  int tid = threadIdx.x;
  int wave = tid>>6, lane = tid&63, quad = lane>>4, lr = lane&15;
  int wm = wave>>1, wn = wave&1;
  int srow = lane>>3, sslot = lane&7;

  floatx4 zero4 = {0.f,0.f,0.f,0.f};
  floatx4 acc[4][4];
  #pragma unroll
  for (int i=0;i<4;i++)
    #pragma unroll
    for (int j=0;j<4;j++) acc[i][j] = zero4;

  #pragma unroll 1
  for (int k0 = 0; k0 < KD; k0 += 64) {
    #pragma unroll
    for (int j=0;j<4;j++) {
      int chunk = wave + j*4;
      int row = chunk*8 + srow;
      int col = ((sslot ^ (row&7)) << 3);
      async_copy16(A + (size_t)(m0+row)*KD + k0 + col, &As[chunk*512]);
      async_copy16(W + (size_t)(n0+row)*KD + k0 + col, &Bs[chunk*512]);
    }
    __syncthreads();
    #pragma unroll
    for (int ks=0; ks<2; ks++) {
      bf16x8 af[4], bfr[4];
      #pragma unroll
      for (int mi=0;mi<4;mi++)
        af[mi] = *(const bf16x8*)&As[(wm*64+mi*16+lr)*64 + (((ks*4+quad) ^ (lr&7))<<3)];
      #pragma unroll
      for (int ni=0;ni<4;ni++)
        bfr[ni] = *(const bf16x8*)&Bs[(wn*64+ni*16+lr)*64 + (((ks*4+quad) ^ (lr&7))<<3)];
      #pragma unroll
      for (int mi=0;mi<4;mi++)
        #pragma unroll
        for (int ni=0;ni<4;ni++)
          acc[mi][ni] = __builtin_amdgcn_mfma_f32_16x16x32_bf16(af[mi], bfr[ni], acc[mi][ni], 0,0,0);
    }
    __syncthreads();
  }

  if (MODE==1) {
    #pragma unroll
    for (int mi=0;mi<4;mi++) {
      int row = m0 + wm*64 + mi*16 + quad*4;
      #pragma unroll
      for (int ni=0;ni<4;ni++) {
        int col = n0 + wn*64 + ni*16 + lr;
        #pragma unroll
        for (int r=0;r<4;r++)
          Cf[(size_t)(row+r)*ND + col] = acc[mi][ni][r];
      }
    }
  } else if (z < 2) {
    bf16_t* Cb = (z==0) ? C0 : C1;
    const float sc = (z==0) ? 0.18033688011112042f : 1.0f;  // 0.125*log2(e)
    #pragma unroll
    for (int mi=0;mi<4;mi++) {
      int row = m0 + wm*64 + mi*16 + quad*4;
      int l = row & 2047;
      #pragma unroll
      for (int ni=0;ni<2;ni++) {
        int col = n0 + wn*64 + ni*16 + lr;
        int f = ni*16 + lr;
        #pragma unroll
        for (int r=0;r<4;r++) {
          float c = cosT[(l+r)*32 + f];
          float s = sinT[(l+r)*32 + f];
          float lo = acc[mi][ni][r], hi = acc[mi][ni+2][r];
          Cb[(size_t)(row+r)*ND + col]      = (bf16_t)((lo*c - hi*s)*sc);
          Cb[(size_t)(row+r)*ND + col + 32] = (bf16_t)((hi*c + lo*s)*sc);
        }
      }
    }
  } else {
    #pragma unroll
    for (int mi=0;mi<4;mi++) {
      int row0 = m0 + wm*64 + mi*16 + quad*4;
      int bb = row0 >> 11, ll = row0 & 2047;
      #pragma unroll
      for (int ni=0;ni<4;ni++) {
        int col = n0 + wn*64 + ni*16 + lr;
        int hh = col >> 6, dd = col & 63;
        uint2 val;
        val.x = pack_bf16(acc[mi][ni][0], acc[mi][ni][1]);
        val.y = pack_bf16(acc[mi][ni][2], acc[mi][ni][3]);
        *(uint2*)&C2[((size_t)((bb<<4)+hh)*64 + dd)*2048 + ll] = val;
      }
    }
  }
}

// ------------------------------ flash attention v8 -------------------------
// grid (64,16,2): x=bh (XCD-local), y=q-tile(128), z=kv-half(1024).
// BKV=32: K(32x64) + V(64x32) LDS tiles double-buffered, 16KB.
// P never touches LDS: QK^T uses row-permuted K (slr = bit2<->bit3 of lr) so
// permlane32_swap pairs produce the PV B-fragment directly. Rowsum = ones-MFMA.
__global__ __launch_bounds__(256) void attn_kernel(
    const bf16_t* __restrict__ Q, const bf16_t* __restrict__ K,
    const bf16_t* __restrict__ Vt, bf16_t* __restrict__ Op,
    float* __restrict__ Ls)
{
  __shared__ __align__(16) bf16_t Ks[2][2048];   // 32kv x 64d  (4KB x2)
  __shared__ __align__(16) bf16_t Vs[2][2048];   // 64d  x 32kv (4KB x2)
  int tid = threadIdx.x;
  int wave = tid>>6, lane = tid&63, quad = lane>>4, lr = lane&15;
  int bh = blockIdx.x; int b = bh>>4, h = bh&15;
  int z = blockIdx.z;
  int q0 = blockIdx.y*128 + wave*32;
  size_t rowQ = (size_t)b*L_ + q0;
  int kvbase = z*1024;

  // QK^T A-row permutation: A-row lr reads K row slr (swap bits 2<->3).
  // Makes P fragment quads contiguous-in-kv so permlane32_swap finishes the
  // relayout to the PV B-fragment.
  int slr = (lr&3) | ((lr&4)<<1) | ((lr&8)>>1);
  int vg  = ((lr>>2) ^ lr) & 3;                  // V read swizzle key

  // staging index maps (landing: base + lane*16B, so fetch swizzled source)
  int ksrow = wave*8 + (lane>>3);                 // K: row kv, 8 rows/wave
  int kscol = (((lane&7) ^ (ksrow&7)) << 3);      // 8-slot XOR swizzle
  int vrow  = tid>>2;                             // V: row d, 16 rows/wave
  int vscol = (((lane&3) ^ (((vrow>>2)^vrow)&3)) << 3); // 8-phase-even swizzle

  bf16x8 qf[2][2];
  #pragma unroll
  for (int n=0;n<2;n++)
    #pragma unroll
    for (int ks=0;ks<2;ks++)
      qf[n][ks] = *(const bf16x8*)&Q[(rowQ + n*16 + lr)*D_ + h*HD_ + ks*32 + quad*8];

  const bf16_t* Kg = K + ((size_t)b*L_ + kvbase)*D_ + h*HD_;
  const bf16_t* Vg = Vt + ((size_t)bh*HD_)*L_ + kvbase;

  bf16x8 onesf;
  #pragma unroll
  for (int j=0;j<8;j++) onesf[j] = (bf16_t)1.0f;

  floatx4 zero4 = {0.f,0.f,0.f,0.f};
  floatx4 accO[2][4];
  floatx4 accS[2];
  accS[0] = zero4; accS[1] = zero4;
  #pragma unroll
  for (int n=0;n<2;n++)
    #pragma unroll
    for (int dt=0;dt<4;dt++) accO[n][dt] = zero4;

  auto stage = [&](int it, int c) {
    async_copy16(Kg + (size_t)(it*32 + ksrow)*D_ + kscol, &Ks[c][wave*512]);
    async_copy16(Vg + (size_t)vrow*L_ + it*32 + vscol,    &Vs[c][wave*512]);
  };

  stage(0, 0);
  __syncthreads();

  #pragma unroll 1
  for (int it = 0; it < 32; ++it) {
    int c = it & 1;
    if (it < 31) stage(it+1, c^1);   // prefetch under compute

    // ---- S^T = K·Q^T : A=K frags (row-permuted via slr), B=Q regs ----
    floatx4 St[2][2];   // [n][t], t = kv subtile of 16
    St[0][0]=zero4; St[0][1]=zero4; St[1][0]=zero4; St[1][1]=zero4;
    __builtin_amdgcn_s_setprio(1);
    #pragma unroll
    for (int t=0;t<2;t++) {
      #pragma unroll
      for (int ks=0;ks<2;ks++) {
        bf16x8 kf = *(const bf16x8*)&Ks[c][(t*16+slr)*64 + (((ks*4+quad) ^ (slr&7))<<3)];
        St[0][t] = __builtin_amdgcn_mfma_f32_16x16x32_bf16(kf, qf[0][ks], St[0][t], 0,0,0);
        St[1][t] = __builtin_amdgcn_mfma_f32_16x16x32_bf16(kf, qf[1][ks], St[1][t], 0,0,0);
      }
    }
    __builtin_amdgcn_s_setprio(0);

    // ---- p = exp2(s) -> packed bf16 -> permlane32_swap -> PV B-frag ----
    // lane(quad,lr) St[n][t][r] = P[kv = t*16 + sigma(quad*4+r)][q=lr]
    //   sigma = bit2<->bit3 swap; so quad kv-runs are contiguous:
    //   Q0:{0-3,16-19} Q1:{8-11,24-27} Q2:{4-7,20-23} Q3:{12-15,28-31}
    // permlane32_swap(w0j, w1j) -> (u[j], u[j+2]) of the B-frag directly.
    bf16x8 pfv[2];
    #pragma unroll
    for (int n=0;n<2;n++) {
      unsigned int w00 = pack_bf16(exp2f(St[n][0][0]), exp2f(St[n][0][1]));
      unsigned int w01 = pack_bf16(exp2f(St[n][0][2]), exp2f(St[n][0][3]));
      unsigned int w10 = pack_bf16(exp2f(St[n][1][0]), exp2f(St[n][1][1]));
      unsigned int w11 = pack_bf16(exp2f(St[n][1][2]), exp2f(St[n][1][3]));
      u32x2 r0 = __builtin_amdgcn_permlane32_swap(w00, w10, false, false);
      u32x2 r1 = __builtin_amdgcn_permlane32_swap(w01, w11, false, false);
      union { unsigned int u[4]; bf16x8 v; } pu;
      pu.u[0] = r0.x; pu.u[1] = r1.x; pu.u[2] = r0.y; pu.u[3] = r1.y;
      pfv[n] = pu.v;
    }

    // ---- O^T += Vt·P^T ; rowsum via ones-MFMA (k=32 one shot) ----
    __builtin_amdgcn_s_setprio(1);
    #pragma unroll
    for (int dt=0;dt<4;dt++) {
      bf16x8 vf = *(const bf16x8*)&Vs[c][(dt*16+lr)*32 + ((quad ^ vg)<<3)];
      accO[0][dt] = __builtin_amdgcn_mfma_f32_16x16x32_bf16(vf, pfv[0], accO[0][dt], 0,0,0);
      accO[1][dt] = __builtin_amdgcn_mfma_f32_16x16x32_bf16(vf, pfv[1], accO[1][dt], 0,0,0);
    }
    accS[0] = __builtin_amdgcn_mfma_f32_16x16x32_bf16(onesf, pfv[0], accS[0], 0,0,0);
    accS[1] = __builtin_amdgcn_mfma_f32_16x16x32_bf16(onesf, pfv[1], accS[1], 0,0,0);
    __builtin_amdgcn_s_setprio(0);

    __syncthreads();   // prefetch landed + tile reads done
  }

  bf16_t* Opz = Op + (size_t)z*M_*D_;
  #pragma unroll
  for (int n=0;n<2;n++) {
    #pragma unroll
    for (int dt=0;dt<4;dt++) {
      uint2 w;
      w.x = pack_bf16(accO[n][dt][0], accO[n][dt][1]);
      w.y = pack_bf16(accO[n][dt][2], accO[n][dt][3]);
      *(uint2*)&Opz[(rowQ + n*16 + lr)*D_ + h*HD_ + dt*16 + quad*4] = w;
    }
  }
  // accS rows are all identical colsums -> element 0 is the denominator.
  if (quad == 0) {
    Ls[z*131072 + bh*2048 + q0 + lr]      = accS[0][0];
    Ls[z*131072 + bh*2048 + q0 + 16 + lr] = accS[1][0];
  }
}

// ------------------------------ reduce -------------------------------------
__global__ void reduce_kernel(const bf16_t* __restrict__ Op, const float* __restrict__ Ls,
                              bf16_t* __restrict__ O)
{
  int i = blockIdx.x*256 + threadIdx.x;   // 2M threads
  size_t e = (size_t)i*4;
  int d  = (int)(e & 1023);
  int bl = (int)(e >> 10);
  int bq = bl >> 11, l = bl & 2047, h = d >> 6;
  int li = (bq*16 + h)*2048 + l;
  float inv = 1.0f / (Ls[li] + Ls[li + 131072]);
  bf16x4 v0 = *(const bf16x4*)&Op[e];
  bf16x4 v1 = *(const bf16x4*)&Op[(size_t)M_*D_ + e];
  bf16x4 r;
  #pragma unroll
  for (int j=0;j<4;j++)
    r[j] = (bf16_t)(((float)v0[j] + (float)v1[j]) * inv);
  *(bf16x4*)&O[e] = r;
}

// ------------------------------ launch -------------------------------------
extern "C" void kernel_launch(void* const* d_in, const int* in_sizes, int n_in,
                              void* d_out, int out_size, void* d_ws, size_t ws_size,
                              hipStream_t stream) {
  const float* x  = (const float*)d_in[0];
  const float* wq = (const float*)d_in[1];
  const float* wk = (const float*)d_in[2];
  const float* wv = (const float*)d_in[3];
  const float* wo = (const float*)d_in[4];

  char* ws = (char*)d_ws;
  bf16_t* xb  = (bf16_t*)(ws);                       // 16MB; reused as O after attn
  bf16_t* Qb  = (bf16_t*)(ws + (size_t)(16u<<20));
  bf16_t* Kb  = (bf16_t*)(ws + (size_t)(32u<<20));
  bf16_t* Vtb = (bf16_t*)(ws + (size_t)(48u<<20));
  bf16_t* wqb = (bf16_t*)(ws + (size_t)(64u<<20));   // dead after gemm<0> -> Ls
  bf16_t* wkb = (bf16_t*)(ws + (size_t)(66u<<20));
  bf16_t* wvb = (bf16_t*)(ws + (size_t)(68u<<20));
  bf16_t* wob = (bf16_t*)(ws + (size_t)(70u<<20));
  float* cosT = (float*)(ws + (size_t)(72u<<20));
  float* sinT = (float*)(ws + (size_t)(72u<<20) + (256u<<10));
  float* Ls   = (float*)wqb;                          // 1MB
  bf16_t* Opart = (bf16_t*)d_out;                     // 32MB scratch; gemm<1> overwrites
  bf16_t* Ob = xb;

  prep_kernel<<<49408, 256, 0, stream>>>(x, wq, wk, wv, wo, xb, wqb, wkb, wvb, wob, cosT, sinT);
  gemm_kernel<0><<<dim3(8,64,3), 256, 0, stream>>>(xb, wqb, wkb, wvb, Qb, Kb, Vtb, nullptr, cosT, sinT);
  attn_kernel<<<dim3(64,16,2), 256, 0, stream>>>(Qb, Kb, Vtb, Opart, Ls);
  reduce_kernel<<<8192, 256, 0, stream>>>(Opart, Ls, Ob);
  gemm_kernel<1><<<dim3(8,64,1), 256, 0, stream>>>(Ob, wob, nullptr, nullptr,
                                                   nullptr, nullptr, nullptr, (float*)d_out, cosT, sinT);
}

// Round 2
// 330.303 us; speedup vs baseline: 1.0244x; 1.0244x over previous
//
#include <hip/hip_runtime.h>

// ---------------------------------------------------------------------------
// MultiHeadSelfAttention  B=4 L=2048 D=1024 H=16 hd=64, fp32 in/out.
//   prep:      x,W -> bf16; rope tables
//   gemm<0>:   Q (rope*0.125*log2e fused), K (rope fused), Vt ([B,H,64,L])
//   attn v9:   = v8 + T4 counted-vmcnt pipeline. 3-buffer K/V ring, stage
//              issued 2 iters ahead, s_waitcnt vmcnt(2) + raw s_barrier per
//              iter (never drain to 0 in the loop). Rationale: v8 deleted
//              ~30% of inner-loop VALU/LDS work with ZERO time delta ->
//              critical path is the m233 2-phase stage+vmcnt(0)+barrier
//              stall, not compute. LDS 24KB.
//   reduce:    O = (O0+O1)/(l0+l1)
//   gemm<1>:   d_out = O @ Wo^T
// R3: no forced min-waves (spills). R4: no reg prefetch (occupancy). R5: no
// per-lane scattered K/V globals. R6: LDS size was the occupancy cap.
// R8: P relayout in-register via slr row-perm + permlane32_swap; rowsum via
//     ones-MFMA (neutral on time, kept: fewer regs, less LDS, cleaner loop).
// ---------------------------------------------------------------------------

typedef __bf16 bf16_t;
typedef __bf16 bf16x8 __attribute__((ext_vector_type(8)));
typedef __bf16 bf16x4 __attribute__((ext_vector_type(4)));
typedef float  floatx4 __attribute__((ext_vector_type(4)));
typedef unsigned int u32x2 __attribute__((ext_vector_type(2)));

#define B_  4
#define L_  2048
#define D_  1024
#define H_  16
#define HD_ 64
#define M_  (B_*L_)

__device__ __forceinline__ void async_copy16(const bf16_t* g, bf16_t* l) {
  __builtin_amdgcn_global_load_lds(
      (const __attribute__((address_space(1))) void*)g,
      (__attribute__((address_space(3))) void*)l, 16, 0, 0);
}

__device__ __forceinline__ unsigned int pack_bf16(float a, float b) {
  unsigned short ua = __builtin_bit_cast(unsigned short, (bf16_t)a);
  unsigned short ub = __builtin_bit_cast(unsigned short, (bf16_t)b);
  return (unsigned int)ua | ((unsigned int)ub << 16);
}

// ------------------------------ prep ---------------------------------------
__global__ void prep_kernel(const float* __restrict__ x,
                            const float* __restrict__ wq, const float* __restrict__ wk,
                            const float* __restrict__ wv, const float* __restrict__ wo,
                            bf16_t* __restrict__ xb,
                            bf16_t* __restrict__ wqb, bf16_t* __restrict__ wkb,
                            bf16_t* __restrict__ wvb, bf16_t* __restrict__ wob,
                            float* __restrict__ cosT, float* __restrict__ sinT)
{
  const int NX = M_*D_;
  const int NW = D_*D_;
  int i = blockIdx.x*256 + threadIdx.x;
  if (i < NX) { xb[i] = (bf16_t)x[i]; return; }
  i -= NX;
  if (i < NW) { wqb[i] = (bf16_t)wq[i]; return; }
  i -= NW;
  if (i < NW) { wkb[i] = (bf16_t)wk[i]; return; }
  i -= NW;
  if (i < NW) { wvb[i] = (bf16_t)wv[i]; return; }
  i -= NW;
  if (i < NW) { wob[i] = (bf16_t)wo[i]; return; }
  i -= NW;
  if (i < L_*32) {
    int l = i >> 5, f = i & 31;
    double inv = pow(10000.0, -(double)f / 32.0);
    double ang = (double)l * inv;
    cosT[i] = (float)cos(ang);
    sinT[i] = (float)sin(ang);
  }
}

// ------------------------------ GEMM (C = A * W^T) -------------------------
template<int MODE>
__global__ __launch_bounds__(256) void gemm_kernel(
    const bf16_t* __restrict__ A,
    const bf16_t* __restrict__ W0, const bf16_t* __restrict__ W1, const bf16_t* __restrict__ W2,
    bf16_t* __restrict__ C0, bf16_t* __restrict__ C1, bf16_t* __restrict__ C2,
    float* __restrict__ Cf,
    const float* __restrict__ cosT, const float* __restrict__ sinT)
{
  __shared__ __align__(16) bf16_t As[128*64];
  __shared__ __align__(16) bf16_t Bs[128*64];
  const int KD = 1024, ND = 1024;
  int z = (MODE==0) ? (int)blockIdx.z : 0;
  const bf16_t* W = (MODE==1) ? W0 : (z==0 ? W0 : (z==1 ? W1 : W2));
  int m0 = blockIdx.y*128, n0 = blockIdx.x*128;
  int tid = threadIdx.x;
  int wave = tid>>6, lane = tid&63, quad = lane>>4, lr = lane&15;
  int wm = wave>>1, wn = wave&1;
  int srow = lane>>3, sslot = lane&7;

  floatx4 zero4 = {0.f,0.f,0.f,0.f};
  floatx4 acc[4][4];
  #pragma unroll
  for (int i=0;i<4;i++)
    #pragma unroll
    for (int j=0;j<4;j++) acc[i][j] = zero4;

  #pragma unroll 1
  for (int k0 = 0; k0 < KD; k0 += 64) {
    #pragma unroll
    for (int j=0;j<4;j++) {
      int chunk = wave + j*4;
      int row = chunk*8 + srow;
      int col = ((sslot ^ (row&7)) << 3);
      async_copy16(A + (size_t)(m0+row)*KD + k0 + col, &As[chunk*512]);
      async_copy16(W + (size_t)(n0+row)*KD + k0 + col, &Bs[chunk*512]);
    }
    __syncthreads();
    #pragma unroll
    for (int ks=0; ks<2; ks++) {
      bf16x8 af[4], bfr[4];
      #pragma unroll
      for (int mi=0;mi<4;mi++)
        af[mi] = *(const bf16x8*)&As[(wm*64+mi*16+lr)*64 + (((ks*4+quad) ^ (lr&7))<<3)];
      #pragma unroll
      for (int ni=0;ni<4;ni++)
        bfr[ni] = *(const bf16x8*)&Bs[(wn*64+ni*16+lr)*64 + (((ks*4+quad) ^ (lr&7))<<3)];
      #pragma unroll
      for (int mi=0;mi<4;mi++)
        #pragma unroll
        for (int ni=0;ni<4;ni++)
          acc[mi][ni] = __builtin_amdgcn_mfma_f32_16x16x32_bf16(af[mi], bfr[ni], acc[mi][ni], 0,0,0);
    }
    __syncthreads();
  }

  if (MODE==1) {
    #pragma unroll
    for (int mi=0;mi<4;mi++) {
      int row = m0 + wm*64 + mi*16 + quad*4;
      #pragma unroll
      for (int ni=0;ni<4;ni++) {
        int col = n0 + wn*64 + ni*16 + lr;
        #pragma unroll
        for (int r=0;r<4;r++)
          Cf[(size_t)(row+r)*ND + col] = acc[mi][ni][r];
      }
    }
  } else if (z < 2) {
    bf16_t* Cb = (z==0) ? C0 : C1;
    const float sc = (z==0) ? 0.18033688011112042f : 1.0f;  // 0.125*log2(e)
    #pragma unroll
    for (int mi=0;mi<4;mi++) {
      int row = m0 + wm*64 + mi*16 + quad*4;
      int l = row & 2047;
      #pragma unroll
      for (int ni=0;ni<2;ni++) {
        int col = n0 + wn*64 + ni*16 + lr;
        int f = ni*16 + lr;
        #pragma unroll
        for (int r=0;r<4;r++) {
          float c = cosT[(l+r)*32 + f];
          float s = sinT[(l+r)*32 + f];
          float lo = acc[mi][ni][r], hi = acc[mi][ni+2][r];
          Cb[(size_t)(row+r)*ND + col]      = (bf16_t)((lo*c - hi*s)*sc);
          Cb[(size_t)(row+r)*ND + col + 32] = (bf16_t)((hi*c + lo*s)*sc);
        }
      }
    }
  } else {
    #pragma unroll
    for (int mi=0;mi<4;mi++) {
      int row0 = m0 + wm*64 + mi*16 + quad*4;
      int bb = row0 >> 11, ll = row0 & 2047;
      #pragma unroll
      for (int ni=0;ni<4;ni++) {
        int col = n0 + wn*64 + ni*16 + lr;
        int hh = col >> 6, dd = col & 63;
        uint2 val;
        val.x = pack_bf16(acc[mi][ni][0], acc[mi][ni][1]);
        val.y = pack_bf16(acc[mi][ni][2], acc[mi][ni][3]);
        *(uint2*)&C2[((size_t)((bb<<4)+hh)*64 + dd)*2048 + ll] = val;
      }
    }
  }
}

// ------------------------------ flash attention v9 -------------------------
// grid (64,16,2): x=bh (XCD-local), y=q-tile(128), z=kv-half(1024).
// BKV=32: K(32x64) + V(64x32) LDS tiles, 3-buffer ring (24KB).
// Pipeline (T3/T4): stage(it+2) at top; compute buf[it%3]; s_waitcnt vmcnt(2)
// (tile it+1 landed, 2 newest loads may fly) + raw s_barrier. Never vmcnt(0)
// in the steady state. Safety: vmcnt is per-wave FIFO and all waves issue
// stages in the same order, so barrier + vmcnt(2) => ALL waves' it+1 loads
// landed; buf[(it+2)%3] was last ds_read at iter it-1, complete (lgkm) before
// that iter's barrier.
__global__ __launch_bounds__(256) void attn_kernel(
    const bf16_t* __restrict__ Q, const bf16_t* __restrict__ K,
    const bf16_t* __restrict__ Vt, bf16_t* __restrict__ Op,
    float* __restrict__ Ls)
{
  __shared__ __align__(16) bf16_t Ks[3][2048];   // 32kv x 64d  (4KB x3)
  __shared__ __align__(16) bf16_t Vs[3][2048];   // 64d  x 32kv (4KB x3)
  int tid = threadIdx.x;
  int wave = tid>>6, lane = tid&63, quad = lane>>4, lr = lane&15;
  int bh = blockIdx.x; int b = bh>>4, h = bh&15;
  int z = blockIdx.z;
  int q0 = blockIdx.y*128 + wave*32;
  size_t rowQ = (size_t)b*L_ + q0;
  int kvbase = z*1024;

  // QK^T A-row permutation: A-row lr reads K row slr (swap bits 2<->3).
  // Makes P fragment quads contiguous-in-kv so permlane32_swap finishes the
  // relayout to the PV B-fragment.
  int slr = (lr&3) | ((lr&4)<<1) | ((lr&8)>>1);
  int vg  = ((lr>>2) ^ lr) & 3;                  // V read swizzle key

  // staging index maps (landing: base + lane*16B, so fetch swizzled source)
  int ksrow = wave*8 + (lane>>3);                 // K: row kv, 8 rows/wave
  int kscol = (((lane&7) ^ (ksrow&7)) << 3);      // 8-slot XOR swizzle
  int vrow  = tid>>2;                             // V: row d, 16 rows/wave
  int vscol = (((lane&3) ^ (((vrow>>2)^vrow)&3)) << 3); // 8-phase-even swizzle

  bf16x8 qf[2][2];
  #pragma unroll
  for (int n=0;n<2;n++)
    #pragma unroll
    for (int ks=0;ks<2;ks++)
      qf[n][ks] = *(const bf16x8*)&Q[(rowQ + n*16 + lr)*D_ + h*HD_ + ks*32 + quad*8];

  const bf16_t* Kg = K + ((size_t)b*L_ + kvbase)*D_ + h*HD_;
  const bf16_t* Vg = Vt + ((size_t)bh*HD_)*L_ + kvbase;

  bf16x8 onesf;
  #pragma unroll
  for (int j=0;j<8;j++) onesf[j] = (bf16_t)1.0f;

  floatx4 zero4 = {0.f,0.f,0.f,0.f};
  floatx4 accO[2][4];
  floatx4 accS[2];
  accS[0] = zero4; accS[1] = zero4;
  #pragma unroll
  for (int n=0;n<2;n++)
    #pragma unroll
    for (int dt=0;dt<4;dt++) accO[n][dt] = zero4;

  auto stage = [&](int it, int c) {
    async_copy16(Kg + (size_t)(it*32 + ksrow)*D_ + kscol, &Ks[c][wave*512]);
    async_copy16(Vg + (size_t)vrow*L_ + it*32 + vscol,    &Vs[c][wave*512]);
  };

  // prologue: two tiles in flight, wait for tile 0 only.
  stage(0, 0);
  stage(1, 1);
  asm volatile("s_waitcnt vmcnt(2)" ::: "memory");
  __builtin_amdgcn_s_barrier();

  #pragma unroll 1
  for (int it = 0; it < 32; ++it) {
    int c = it % 3;
    if (it < 30) stage(it+2, (it+2) % 3);   // 2-deep prefetch

    // ---- S^T = K·Q^T : A=K frags (row-permuted via slr), B=Q regs ----
    floatx4 St[2][2];   // [n][t], t = kv subtile of 16
    St[0][0]=zero4; St[0][1]=zero4; St[1][0]=zero4; St[1][1]=zero4;
    __builtin_amdgcn_s_setprio(1);
    #pragma unroll
    for (int t=0;t<2;t++) {
      #pragma unroll
      for (int ks=0;ks<2;ks++) {
        bf16x8 kf = *(const bf16x8*)&Ks[c][(t*16+slr)*64 + (((ks*4+quad) ^ (slr&7))<<3)];
        St[0][t] = __builtin_amdgcn_mfma_f32_16x16x32_bf16(kf, qf[0][ks], St[0][t], 0,0,0);
        St[1][t] = __builtin_amdgcn_mfma_f32_16x16x32_bf16(kf, qf[1][ks], St[1][t], 0,0,0);
      }
    }
    __builtin_amdgcn_s_setprio(0);

    // ---- p = exp2(s) -> packed bf16 -> permlane32_swap -> PV B-frag ----
    // lane(quad,lr) St[n][t][r] = P[kv = t*16 + sigma(quad*4+r)][q=lr]
    //   sigma = bit2<->bit3 swap; so quad kv-runs are contiguous:
    //   Q0:{0-3,16-19} Q1:{8-11,24-27} Q2:{4-7,20-23} Q3:{12-15,28-31}
    // permlane32_swap(w0j, w1j) -> (u[j], u[j+2]) of the B-frag directly.
    bf16x8 pfv[2];
    #pragma unroll
    for (int n=0;n<2;n++) {
      unsigned int w00 = pack_bf16(exp2f(St[n][0][0]), exp2f(St[n][0][1]));
      unsigned int w01 = pack_bf16(exp2f(St[n][0][2]), exp2f(St[n][0][3]));
      unsigned int w10 = pack_bf16(exp2f(St[n][1][0]), exp2f(St[n][1][1]));
      unsigned int w11 = pack_bf16(exp2f(St[n][1][2]), exp2f(St[n][1][3]));
      u32x2 r0 = __builtin_amdgcn_permlane32_swap(w00, w10, false, false);
      u32x2 r1 = __builtin_amdgcn_permlane32_swap(w01, w11, false, false);
      union { unsigned int u[4]; bf16x8 v; } pu;
      pu.u[0] = r0.x; pu.u[1] = r1.x; pu.u[2] = r0.y; pu.u[3] = r1.y;
      pfv[n] = pu.v;
    }

    // ---- O^T += Vt·P^T ; rowsum via ones-MFMA (k=32 one shot) ----
    __builtin_amdgcn_s_setprio(1);
    #pragma unroll
    for (int dt=0;dt<4;dt++) {
      bf16x8 vf = *(const bf16x8*)&Vs[c][(dt*16+lr)*32 + ((quad ^ vg)<<3)];
      accO[0][dt] = __builtin_amdgcn_mfma_f32_16x16x32_bf16(vf, pfv[0], accO[0][dt], 0,0,0);
      accO[1][dt] = __builtin_amdgcn_mfma_f32_16x16x32_bf16(vf, pfv[1], accO[1][dt], 0,0,0);
    }
    accS[0] = __builtin_amdgcn_mfma_f32_16x16x32_bf16(onesf, pfv[0], accS[0], 0,0,0);
    accS[1] = __builtin_amdgcn_mfma_f32_16x16x32_bf16(onesf, pfv[1], accS[1], 0,0,0);
    __builtin_amdgcn_s_setprio(0);

    // counted drain: tile it+1 must be landed; the 2 loads of tile it+2 may fly.
    if (it < 30) {
      asm volatile("s_waitcnt vmcnt(2)" ::: "memory");
    } else {
      asm volatile("s_waitcnt vmcnt(0)" ::: "memory");
    }
    __builtin_amdgcn_s_barrier();
  }

  bf16_t* Opz = Op + (size_t)z*M_*D_;
  #pragma unroll
  for (int n=0;n<2;n++) {
    #pragma unroll
    for (int dt=0;dt<4;dt++) {
      uint2 w;
      w.x = pack_bf16(accO[n][dt][0], accO[n][dt][1]);
      w.y = pack_bf16(accO[n][dt][2], accO[n][dt][3]);
      *(uint2*)&Opz[(rowQ + n*16 + lr)*D_ + h*HD_ + dt*16 + quad*4] = w;
    }
  }
  // accS rows are all identical colsums -> element 0 is the denominator.
  if (quad == 0) {
    Ls[z*131072 + bh*2048 + q0 + lr]      = accS[0][0];
    Ls[z*131072 + bh*2048 + q0 + 16 + lr] = accS[1][0];
  }
}

// ------------------------------ reduce -------------------------------------
__global__ void reduce_kernel(const bf16_t* __restrict__ Op, const float* __restrict__ Ls,
                              bf16_t* __restrict__ O)
{
  int i = blockIdx.x*256 + threadIdx.x;   // 2M threads
  size_t e = (size_t)i*4;
  int d  = (int)(e & 1023);
  int bl = (int)(e >> 10);
  int bq = bl >> 11, l = bl & 2047, h = d >> 6;
  int li = (bq*16 + h)*2048 + l;
  float inv = 1.0f / (Ls[li] + Ls[li + 131072]);
  bf16x4 v0 = *(const bf16x4*)&Op[e];
  bf16x4 v1 = *(const bf16x4*)&Op[(size_t)M_*D_ + e];
  bf16x4 r;
  #pragma unroll
  for (int j=0;j<4;j++)
    r[j] = (bf16_t)(((float)v0[j] + (float)v1[j]) * inv);
  *(bf16x4*)&O[e] = r;
}

// ------------------------------ launch -------------------------------------
extern "C" void kernel_launch(void* const* d_in, const int* in_sizes, int n_in,
                              void* d_out, int out_size, void* d_ws, size_t ws_size,
                              hipStream_t stream) {
  const float* x  = (const float*)d_in[0];
  const float* wq = (const float*)d_in[1];
  const float* wk = (const float*)d_in[2];
  const float* wv = (const float*)d_in[3];
  const float* wo = (const float*)d_in[4];

  char* ws = (char*)d_ws;
  bf16_t* xb  = (bf16_t*)(ws);                       // 16MB; reused as O after attn
  bf16_t* Qb  = (bf16_t*)(ws + (size_t)(16u<<20));
  bf16_t* Kb  = (bf16_t*)(ws + (size_t)(32u<<20));
  bf16_t* Vtb = (bf16_t*)(ws + (size_t)(48u<<20));
  bf16_t* wqb = (bf16_t*)(ws + (size_t)(64u<<20));   // dead after gemm<0> -> Ls
  bf16_t* wkb = (bf16_t*)(ws + (size_t)(66u<<20));
  bf16_t* wvb = (bf16_t*)(ws + (size_t)(68u<<20));
  bf16_t* wob = (bf16_t*)(ws + (size_t)(70u<<20));
  float* cosT = (float*)(ws + (size_t)(72u<<20));
  float* sinT = (float*)(ws + (size_t)(72u<<20) + (256u<<10));
  float* Ls   = (float*)wqb;                          // 1MB
  bf16_t* Opart = (bf16_t*)d_out;                     // 32MB scratch; gemm<1> overwrites
  bf16_t* Ob = xb;

  prep_kernel<<<49408, 256, 0, stream>>>(x, wq, wk, wv, wo, xb, wqb, wkb, wvb, wob, cosT, sinT);
  gemm_kernel<0><<<dim3(8,64,3), 256, 0, stream>>>(xb, wqb, wkb, wvb, Qb, Kb, Vtb, nullptr, cosT, sinT);
  attn_kernel<<<dim3(64,16,2), 256, 0, stream>>>(Qb, Kb, Vtb, Opart, Ls);
  reduce_kernel<<<8192, 256, 0, stream>>>(Opart, Ls, Ob);
  gemm_kernel<1><<<dim3(8,64,1), 256, 0, stream>>>(Ob, wob, nullptr, nullptr,
                                                   nullptr, nullptr, nullptr, (float*)d_out, cosT, sinT);
}

// Round 3
// 326.166 us; speedup vs baseline: 1.0374x; 1.0127x over previous
//
#include <hip/hip_runtime.h>

// ---------------------------------------------------------------------------
// MultiHeadSelfAttention  B=4 L=2048 D=1024 H=16 hd=64, fp32 in/out.
//   prep:      x,W -> bf16; rope tables
//   gemm<0>:   Q (rope*0.125*log2e fused), K (rope fused), Vt ([B,H,64,L])
//   attn v10:  KVBLK=64 (half the barrier rounds), z-split merged (one pass
//              over all 2048 kv; no partial-O / no reduce kernel), V tile
//              [64d][64kv] so V reads use the same 8-slot XOR pattern as K,
//              ring-3 buffers (48KB LDS), 2-deep prefetch, counted vmcnt(4),
//              setprio removed (m190: negative on barrier-lockstep blocks).
//              Rationale: v8 (-30% inner work) and v9 (counted vmcnt) were
//              both NULL -> stall is the per-round barrier convoy, so reduce
//              the number of rounds, not the work per round.
//   gemm<1>:   d_out = O @ Wo^T
// R3: no forced min-waves (spills). R4: no reg prefetch (occupancy). R5: no
// per-lane scattered K/V globals. R6: LDS size was the occupancy cap.
// R8: P relayout in-register via slr row-perm + permlane32_swap; rowsum via
//     ones-MFMA (kept: fewer regs, no P LDS traffic).
// R9: counted vmcnt + 3-ring (kept, neutral alone).
// ---------------------------------------------------------------------------

typedef __bf16 bf16_t;
typedef __bf16 bf16x8 __attribute__((ext_vector_type(8)));
typedef __bf16 bf16x4 __attribute__((ext_vector_type(4)));
typedef float  floatx4 __attribute__((ext_vector_type(4)));
typedef unsigned int u32x2 __attribute__((ext_vector_type(2)));

#define B_  4
#define L_  2048
#define D_  1024
#define H_  16
#define HD_ 64
#define M_  (B_*L_)

__device__ __forceinline__ void async_copy16(const bf16_t* g, bf16_t* l) {
  __builtin_amdgcn_global_load_lds(
      (const __attribute__((address_space(1))) void*)g,
      (__attribute__((address_space(3))) void*)l, 16, 0, 0);
}

__device__ __forceinline__ unsigned int pack_bf16(float a, float b) {
  unsigned short ua = __builtin_bit_cast(unsigned short, (bf16_t)a);
  unsigned short ub = __builtin_bit_cast(unsigned short, (bf16_t)b);
  return (unsigned int)ua | ((unsigned int)ub << 16);
}

// ------------------------------ prep ---------------------------------------
__global__ void prep_kernel(const float* __restrict__ x,
                            const float* __restrict__ wq, const float* __restrict__ wk,
                            const float* __restrict__ wv, const float* __restrict__ wo,
                            bf16_t* __restrict__ xb,
                            bf16_t* __restrict__ wqb, bf16_t* __restrict__ wkb,
                            bf16_t* __restrict__ wvb, bf16_t* __restrict__ wob,
                            float* __restrict__ cosT, float* __restrict__ sinT)
{
  const int NX = M_*D_;
  const int NW = D_*D_;
  int i = blockIdx.x*256 + threadIdx.x;
  if (i < NX) { xb[i] = (bf16_t)x[i]; return; }
  i -= NX;
  if (i < NW) { wqb[i] = (bf16_t)wq[i]; return; }
  i -= NW;
  if (i < NW) { wkb[i] = (bf16_t)wk[i]; return; }
  i -= NW;
  if (i < NW) { wvb[i] = (bf16_t)wv[i]; return; }
  i -= NW;
  if (i < NW) { wob[i] = (bf16_t)wo[i]; return; }
  i -= NW;
  if (i < L_*32) {
    int l = i >> 5, f = i & 31;
    double inv = pow(10000.0, -(double)f / 32.0);
    double ang = (double)l * inv;
    cosT[i] = (float)cos(ang);
    sinT[i] = (float)sin(ang);
  }
}

// ------------------------------ GEMM (C = A * W^T) -------------------------
template<int MODE>
__global__ __launch_bounds__(256) void gemm_kernel(
    const bf16_t* __restrict__ A,
    const bf16_t* __restrict__ W0, const bf16_t* __restrict__ W1, const bf16_t* __restrict__ W2,
    bf16_t* __restrict__ C0, bf16_t* __restrict__ C1, bf16_t* __restrict__ C2,
    float* __restrict__ Cf,
    const float* __restrict__ cosT, const float* __restrict__ sinT)
{
  __shared__ __align__(16) bf16_t As[128*64];
  __shared__ __align__(16) bf16_t Bs[128*64];
  const int KD = 1024, ND = 1024;
  int z = (MODE==0) ? (int)blockIdx.z : 0;
  const bf16_t* W = (MODE==1) ? W0 : (z==0 ? W0 : (z==1 ? W1 : W2));
  int m0 = blockIdx.y*128, n0 = blockIdx.x*128;
  int tid = threadIdx.x;
  int wave = tid>>6, lane = tid&63, quad = lane>>4, lr = lane&15;
  int wm = wave>>1, wn = wave&1;
  int srow = lane>>3, sslot = lane&7;

  floatx4 zero4 = {0.f,0.f,0.f,0.f};
  floatx4 acc[4][4];
  #pragma unroll
  for (int i=0;i<4;i++)
    #pragma unroll
    for (int j=0;j<4;j++) acc[i][j] = zero4;

  #pragma unroll 1
  for (int k0 = 0; k0 < KD; k0 += 64) {
    #pragma unroll
    for (int j=0;j<4;j++) {
      int chunk = wave + j*4;
      int row = chunk*8 + srow;
      int col = ((sslot ^ (row&7)) << 3);
      async_copy16(A + (size_t)(m0+row)*KD + k0 + col, &As[chunk*512]);
      async_copy16(W + (size_t)(n0+row)*KD + k0 + col, &Bs[chunk*512]);
    }
    __syncthreads();
    #pragma unroll
    for (int ks=0; ks<2; ks++) {
      bf16x8 af[4], bfr[4];
      #pragma unroll
      for (int mi=0;mi<4;mi++)
        af[mi] = *(const bf16x8*)&As[(wm*64+mi*16+lr)*64 + (((ks*4+quad) ^ (lr&7))<<3)];
      #pragma unroll
      for (int ni=0;ni<4;ni++)
        bfr[ni] = *(const bf16x8*)&Bs[(wn*64+ni*16+lr)*64 + (((ks*4+quad) ^ (lr&7))<<3)];
      #pragma unroll
      for (int mi=0;mi<4;mi++)
        #pragma unroll
        for (int ni=0;ni<4;ni++)
          acc[mi][ni] = __builtin_amdgcn_mfma_f32_16x16x32_bf16(af[mi], bfr[ni], acc[mi][ni], 0,0,0);
    }
    __syncthreads();
  }

  if (MODE==1) {
    #pragma unroll
    for (int mi=0;mi<4;mi++) {
      int row = m0 + wm*64 + mi*16 + quad*4;
      #pragma unroll
      for (int ni=0;ni<4;ni++) {
        int col = n0 + wn*64 + ni*16 + lr;
        #pragma unroll
        for (int r=0;r<4;r++)
          Cf[(size_t)(row+r)*ND + col] = acc[mi][ni][r];
      }
    }
  } else if (z < 2) {
    bf16_t* Cb = (z==0) ? C0 : C1;
    const float sc = (z==0) ? 0.18033688011112042f : 1.0f;  // 0.125*log2(e)
    #pragma unroll
    for (int mi=0;mi<4;mi++) {
      int row = m0 + wm*64 + mi*16 + quad*4;
      int l = row & 2047;
      #pragma unroll
      for (int ni=0;ni<2;ni++) {
        int col = n0 + wn*64 + ni*16 + lr;
        int f = ni*16 + lr;
        #pragma unroll
        for (int r=0;r<4;r++) {
          float c = cosT[(l+r)*32 + f];
          float s = sinT[(l+r)*32 + f];
          float lo = acc[mi][ni][r], hi = acc[mi][ni+2][r];
          Cb[(size_t)(row+r)*ND + col]      = (bf16_t)((lo*c - hi*s)*sc);
          Cb[(size_t)(row+r)*ND + col + 32] = (bf16_t)((hi*c + lo*s)*sc);
        }
      }
    }
  } else {
    #pragma unroll
    for (int mi=0;mi<4;mi++) {
      int row0 = m0 + wm*64 + mi*16 + quad*4;
      int bb = row0 >> 11, ll = row0 & 2047;
      #pragma unroll
      for (int ni=0;ni<4;ni++) {
        int col = n0 + wn*64 + ni*16 + lr;
        int hh = col >> 6, dd = col & 63;
        uint2 val;
        val.x = pack_bf16(acc[mi][ni][0], acc[mi][ni][1]);
        val.y = pack_bf16(acc[mi][ni][2], acc[mi][ni][3]);
        *(uint2*)&C2[((size_t)((bb<<4)+hh)*64 + dd)*2048 + ll] = val;
      }
    }
  }
}

// ------------------------------ flash attention v10 ------------------------
// grid (64,16): x=bh (XCD-local: per XCD 8 bh x 512KB K/V = 4MB = L2), y=q128.
// KVBLK=64: K(64x64) + V(64d x 64kv) tiles, ring-3 (48KB LDS -> 3 blocks/CU).
// 32 iters over all 2048 kv; stage(it+2), wait vmcnt(4) (tile it+1 landed,
// tile it+2's 4 instrs in flight), raw s_barrier once per iter.
// Safety: all waves stage in identical order; vmcnt(4)+barrier => tile it+1
// fully landed; buf[(it+2)%3] last ds_read at iter it-1, consumed before that
// iter's barrier (reads feed MFMAs issued before the barrier).
__global__ __launch_bounds__(256) void attn_kernel(
    const bf16_t* __restrict__ Q, const bf16_t* __restrict__ K,
    const bf16_t* __restrict__ Vt, bf16_t* __restrict__ O)
{
  __shared__ __align__(16) bf16_t Ks[3][4096];   // 64kv x 64d  (8KB x3)
  __shared__ __align__(16) bf16_t Vs[3][4096];   // 64d  x 64kv (8KB x3)
  int tid = threadIdx.x;
  int wave = tid>>6, lane = tid&63, quad = lane>>4, lr = lane&15;
  int bh = blockIdx.x; int b = bh>>4, h = bh&15;
  int q0 = blockIdx.y*128 + wave*32;
  size_t rowQ = (size_t)b*L_ + q0;

  // QK^T A-row permutation: A-row lr reads K row slr (swap bits 2<->3).
  // Makes P fragment quads contiguous-in-kv so permlane32_swap finishes the
  // relayout to the PV B-fragment.
  int slr = (lr&3) | ((lr&4)<<1) | ((lr&8)>>1);

  // staging map: per instr 8 rows x 128B; landing = base + lane*16B, so the
  // 16B slot (lane&7) fetches the XOR-swizzled source column.
  int srow8 = lane>>3;                            // row within 8-row chunk
  int sslot = lane&7;                             // 16B slot within 128B row

  bf16x8 qf[2][2];
  #pragma unroll
  for (int n=0;n<2;n++)
    #pragma unroll
    for (int ks=0;ks<2;ks++)
      qf[n][ks] = *(const bf16x8*)&Q[(rowQ + n*16 + lr)*D_ + h*HD_ + ks*32 + quad*8];

  const bf16_t* Kg = K + (size_t)b*L_*D_ + h*HD_;
  const bf16_t* Vg = Vt + (size_t)bh*HD_*L_;

  bf16x8 onesf;
  #pragma unroll
  for (int j=0;j<8;j++) onesf[j] = (bf16_t)1.0f;

  floatx4 zero4 = {0.f,0.f,0.f,0.f};
  floatx4 accO[2][4];
  floatx4 accS[2];
  accS[0] = zero4; accS[1] = zero4;
  #pragma unroll
  for (int n=0;n<2;n++)
    #pragma unroll
    for (int dt=0;dt<4;dt++) accO[n][dt] = zero4;

  auto stage = [&](int it, int c) {
    #pragma unroll
    for (int j=0;j<2;j++) {
      int row = wave*16 + j*8 + srow8;
      int col = ((sslot ^ (row&7)) << 3);
      async_copy16(Kg + (size_t)(it*64 + row)*D_ + col, &Ks[c][(wave*16 + j*8)*64]);
      async_copy16(Vg + (size_t)row*L_ + it*64 + col,   &Vs[c][(wave*16 + j*8)*64]);
    }
  };

  // prologue: two tiles in flight, wait for tile 0 only (8 out -> <=4).
  stage(0, 0);
  stage(1, 1);
  asm volatile("s_waitcnt vmcnt(4)" ::: "memory");
  __builtin_amdgcn_s_barrier();

  #pragma unroll 1
  for (int it = 0; it < 32; ++it) {
    int c = it % 3;
    if (it < 30) stage(it+2, (it+2) % 3);   // 2-deep prefetch

    // ---- S^T = K·Q^T : A=K frags (row-permuted via slr), B=Q regs ----
    floatx4 St[2][4];   // [n][t], t = kv subtile of 16
    #pragma unroll
    for (int t=0;t<4;t++) { St[0][t]=zero4; St[1][t]=zero4; }
    #pragma unroll
    for (int t=0;t<4;t++) {
      #pragma unroll
      for (int ks=0;ks<2;ks++) {
        bf16x8 kf = *(const bf16x8*)&Ks[c][(t*16+slr)*64 + (((ks*4+quad) ^ (slr&7))<<3)];
        St[0][t] = __builtin_amdgcn_mfma_f32_16x16x32_bf16(kf, qf[0][ks], St[0][t], 0,0,0);
        St[1][t] = __builtin_amdgcn_mfma_f32_16x16x32_bf16(kf, qf[1][ks], St[1][t], 0,0,0);
      }
    }

    // ---- p = exp2(s) -> packed bf16 -> permlane32_swap -> PV B-frags ----
    // Within each 32-kv half hh (t-pair 2hh,2hh+1):
    // lane(quad,lr) St[n][t][r] = P[kv = t*16 + sigma(quad*4+r)][q=lr],
    // sigma = bit2<->bit3 swap; permlane32_swap(w0j, w1j) -> (u[j], u[j+2]).
    bf16x8 pfv[2][2];
    #pragma unroll
    for (int n=0;n<2;n++) {
      #pragma unroll
      for (int hh=0;hh<2;hh++) {
        unsigned int w00 = pack_bf16(exp2f(St[n][2*hh][0]),   exp2f(St[n][2*hh][1]));
        unsigned int w01 = pack_bf16(exp2f(St[n][2*hh][2]),   exp2f(St[n][2*hh][3]));
        unsigned int w10 = pack_bf16(exp2f(St[n][2*hh+1][0]), exp2f(St[n][2*hh+1][1]));
        unsigned int w11 = pack_bf16(exp2f(St[n][2*hh+1][2]), exp2f(St[n][2*hh+1][3]));
        u32x2 r0 = __builtin_amdgcn_permlane32_swap(w00, w10, false, false);
        u32x2 r1 = __builtin_amdgcn_permlane32_swap(w01, w11, false, false);
        union { unsigned int u[4]; bf16x8 v; } pu;
        pu.u[0] = r0.x; pu.u[1] = r1.x; pu.u[2] = r0.y; pu.u[3] = r1.y;
        pfv[n][hh] = pu.v;
      }
    }

    // ---- O^T += Vt·P^T ; rowsum via ones-MFMA ----
    #pragma unroll
    for (int dt=0;dt<4;dt++) {
      #pragma unroll
      for (int hh=0;hh<2;hh++) {
        bf16x8 vf = *(const bf16x8*)&Vs[c][(dt*16+lr)*64 + (((hh*4+quad) ^ (lr&7))<<3)];
        accO[0][dt] = __builtin_amdgcn_mfma_f32_16x16x32_bf16(vf, pfv[0][hh], accO[0][dt], 0,0,0);
        accO[1][dt] = __builtin_amdgcn_mfma_f32_16x16x32_bf16(vf, pfv[1][hh], accO[1][dt], 0,0,0);
      }
    }
    accS[0] = __builtin_amdgcn_mfma_f32_16x16x32_bf16(onesf, pfv[0][0], accS[0], 0,0,0);
    accS[1] = __builtin_amdgcn_mfma_f32_16x16x32_bf16(onesf, pfv[1][0], accS[1], 0,0,0);
    accS[0] = __builtin_amdgcn_mfma_f32_16x16x32_bf16(onesf, pfv[0][1], accS[0], 0,0,0);
    accS[1] = __builtin_amdgcn_mfma_f32_16x16x32_bf16(onesf, pfv[1][1], accS[1], 0,0,0);

    // counted drain: tile it+1 landed; the 4 loads of tile it+2 may fly.
    if (it < 30) {
      asm volatile("s_waitcnt vmcnt(4)" ::: "memory");
    } else {
      asm volatile("s_waitcnt vmcnt(0)" ::: "memory");
    }
    __builtin_amdgcn_s_barrier();
  }

  // ---- epilogue: per-lane normalize (accS col q=lr lives in this lane) ----
  float inv0 = 1.0f / accS[0][0];
  float inv1 = 1.0f / accS[1][0];
  #pragma unroll
  for (int n=0;n<2;n++) {
    float inv = n ? inv1 : inv0;
    #pragma unroll
    for (int dt=0;dt<4;dt++) {
      uint2 w;
      w.x = pack_bf16(accO[n][dt][0]*inv, accO[n][dt][1]*inv);
      w.y = pack_bf16(accO[n][dt][2]*inv, accO[n][dt][3]*inv);
      *(uint2*)&O[(rowQ + n*16 + lr)*D_ + h*HD_ + dt*16 + quad*4] = w;
    }
  }
}

// ------------------------------ launch -------------------------------------
extern "C" void kernel_launch(void* const* d_in, const int* in_sizes, int n_in,
                              void* d_out, int out_size, void* d_ws, size_t ws_size,
                              hipStream_t stream) {
  const float* x  = (const float*)d_in[0];
  const float* wq = (const float*)d_in[1];
  const float* wk = (const float*)d_in[2];
  const float* wv = (const float*)d_in[3];
  const float* wo = (const float*)d_in[4];

  char* ws = (char*)d_ws;
  bf16_t* xb  = (bf16_t*)(ws);                       // 16MB; reused as O after attn
  bf16_t* Qb  = (bf16_t*)(ws + (size_t)(16u<<20));
  bf16_t* Kb  = (bf16_t*)(ws + (size_t)(32u<<20));
  bf16_t* Vtb = (bf16_t*)(ws + (size_t)(48u<<20));
  bf16_t* wqb = (bf16_t*)(ws + (size_t)(64u<<20));
  bf16_t* wkb = (bf16_t*)(ws + (size_t)(66u<<20));
  bf16_t* wvb = (bf16_t*)(ws + (size_t)(68u<<20));
  bf16_t* wob = (bf16_t*)(ws + (size_t)(70u<<20));
  float* cosT = (float*)(ws + (size_t)(72u<<20));
  float* sinT = (float*)(ws + (size_t)(72u<<20) + (256u<<10));
  bf16_t* Ob = xb;

  prep_kernel<<<49408, 256, 0, stream>>>(x, wq, wk, wv, wo, xb, wqb, wkb, wvb, wob, cosT, sinT);
  gemm_kernel<0><<<dim3(8,64,3), 256, 0, stream>>>(xb, wqb, wkb, wvb, Qb, Kb, Vtb, nullptr, cosT, sinT);
  attn_kernel<<<dim3(64,16), 256, 0, stream>>>(Qb, Kb, Vtb, Ob);
  gemm_kernel<1><<<dim3(8,64,1), 256, 0, stream>>>(Ob, wob, nullptr, nullptr,
                                                   nullptr, nullptr, nullptr, (float*)d_out, cosT, sinT);
}